// Round 1
// baseline (3774.539 us; speedup 1.0000x reference)
//
#include <hip/hip_runtime.h>

typedef __bf16 bf16x8 __attribute__((ext_vector_type(8)));
typedef float f32x4 __attribute__((ext_vector_type(4)));

// ---------------- numerics helpers (bit-exact vs reference) ----------------

__device__ __forceinline__ unsigned short f32_to_bf16_bits(float v) {
  return (unsigned short)(__float_as_uint(v) >> 16);
}

__device__ __forceinline__ float round_e4m3_pos(float a) {
  float am = fmaxf(a, 0x1p-9f);
  int e = (int)((__float_as_uint(am) >> 23) & 255) - 127;
  e = e < -6 ? -6 : (e > 8 ? 8 : e);
  float s = __int_as_float((e + 127) << 23);
  float q = rintf(a / s * 8.0f) * 0.125f * s;
  return fminf(q, 448.0f);
}

__device__ __forceinline__ float round_e2m1(float x) {
  float a = fabsf(x);
  float am = fmaxf(a, 0x1p-3f);
  int e = (int)((__float_as_uint(am) >> 23) & 255) - 127;
  e = e < 0 ? 0 : (e > 2 ? 2 : e);
  float s = __int_as_float((e + 127) << 23);
  float q = rintf(a / s * 2.0f) * 0.5f * s;
  q = fminf(q, 6.0f);
  return x < 0.0f ? -q : q;
}

__device__ __forceinline__ void g2l16(const void* g, void* l) {
  __builtin_amdgcn_global_load_lds(
      (__attribute__((address_space(1))) void*)g,
      (__attribute__((address_space(3))) void*)l, 16, 0, 0);
}

// ---------------- prep kernels (unchanged, harness-verified) ----------------

__global__ void init_kernel(unsigned* p) {
  if (threadIdx.x < 2) p[threadIdx.x] = 0u;
}

__global__ __launch_bounds__(256) void amax_kernel(const float4* __restrict__ w,
                                                   unsigned* __restrict__ out, int n4) {
  float m = 0.0f;
  int stride = gridDim.x * 256;
  for (int i = blockIdx.x * 256 + threadIdx.x; i < n4; i += stride) {
    float4 v = w[i];
    m = fmaxf(m, fmaxf(fmaxf(fabsf(v.x), fabsf(v.y)), fmaxf(fabsf(v.z), fabsf(v.w))));
  }
#pragma unroll
  for (int o = 32; o > 0; o >>= 1) m = fmaxf(m, __shfl_xor(m, o, 64));
  if ((threadIdx.x & 63) == 0) atomicMax(out, __float_as_uint(m));
}

__global__ __launch_bounds__(256) void quant_kernel(const float4* __restrict__ in,
                                                    ushort* __restrict__ outq,
                                                    const float* __restrict__ tsp,
                                                    const unsigned* __restrict__ amaxp,
                                                    int isw, int n4) {
  int i = blockIdx.x * 256 + threadIdx.x;
  if (i >= n4) return;
  float ts = isw ? (__uint_as_float(*amaxp) / 2688.0f) : *tsp;
  float4 v = in[i];
  float m = fmaxf(fmaxf(fabsf(v.x), fabsf(v.y)), fmaxf(fabsf(v.z), fabsf(v.w)));
  m = fmaxf(m, __shfl_xor(m, 1, 64));
  m = fmaxf(m, __shfl_xor(m, 2, 64));
  float bs = fmaxf(round_e4m3_pos(m / (6.0f * ts)), 0x1p-6f);
  float eff = bs * ts;
  float osc = isw ? bs : eff;
  ushort4 o;
  o.x = f32_to_bf16_bits(round_e2m1(v.x / eff) * osc);
  o.y = f32_to_bf16_bits(round_e2m1(v.y / eff) * osc);
  o.z = f32_to_bf16_bits(round_e2m1(v.z / eff) * osc);
  o.w = f32_to_bf16_bits(round_e2m1(v.w / eff) * osc);
  *(ushort4*)(outq + (size_t)i * 4) = o;
}

// ---------------- GEMM: 256x256 tile, BK=64, 8 waves, 8-phase pipeline ----------------
// LDS map (128 KiB): A: buf d at smem + d*32768, layout [ksub(2)][row(256)][kc(32)] bf16,
//                    B: same at smem + 65536 + d*32768.
// Swizzle (involution, bits>=4 only): a ^= ((a>>3) & 0x30)  [row bits 1,2 -> bank bits 4,5]
//   -> stride-64B ds_read_b128 fragment reads become 2-way (free).
//   Staging keeps LINEAR LDS dest (global_load_lds requirement) + inverse-swizzled
//   global source; read side applies the same XOR.
// Staging ledger (per tile t, buf d=t&1): ph1: B-k1(t+1)->d^1, ph2: A-k0(t+2)->d,
//   ph3: B-k0(t+2)->d, ph4: A-k1(t+2)->d, then s_waitcnt vmcnt(6) (retires exactly
//   all 4 halves of tile t+1; 3 halves of t+2 stay in flight). Every stage-issue is
//   one barrier after its region's last read. Tail clamps source k (redundant loads,
//   regions already consumed).

#define FENCE asm volatile("" ::: "memory")
#define SBAR { FENCE; __builtin_amdgcn_s_barrier(); FENCE; }

template <int EPI>
__global__ __launch_bounds__(512, 2) void gemm256(const ushort* __restrict__ A,
                                                  const ushort* __restrict__ B,
                                                  void* __restrict__ Out,
                                                  const unsigned* __restrict__ amaxp,
                                                  const float* __restrict__ tshp,
                                                  int N, int K) {
  __shared__ __align__(16) char smem[131072];
  const int tid = threadIdx.x;
  const int lane = tid & 63, wv = tid >> 6;
  const int wm = wv >> 2, wn = wv & 3;   // 2 x 4 wave grid
  const int lr = lane & 15, lq = lane >> 4;

  // XCD-aware bijective swizzle (grid %8 == 0 for both GEMMs here)
  const int nwg = gridDim.x;
  const int wg = (blockIdx.x & 7) * (nwg >> 3) + (blockIdx.x >> 3);
  const int ntiles = N >> 8;
  const int bm = wg / ntiles, bn = wg - bm * ntiles;
  const size_t arow0 = (size_t)bm << 8, brow0 = (size_t)bn << 8;

  // ---- staging: per-thread source coords (inverse-swizzled), linear LDS dest ----
  const int sw = (tid << 4) ^ ((tid << 1) & 0x30);  // swizzled unit-offset of chunk tid
  const int srow = sw >> 6;                          // 0..127 (chunk tid+512 -> +128)
  const int skc = (sw & 63) >> 1;                    // element offset in k-half
  const ushort* gA0 = A + (arow0 + srow) * (size_t)K + skc;
  const ushort* gA1 = gA0 + (size_t)128 * K;
  const ushort* gB0 = B + (brow0 + srow) * (size_t)K + skc;
  const ushort* gB1 = gB0 + (size_t)128 * K;
  char* lA = smem + tid * 16;
  char* lB = smem + 65536 + tid * 16;

#define STAGE_A(d, ksub, ko)                                      \
  {                                                               \
    g2l16(gA0 + (ko), lA + (d) * 32768 + (ksub) * 16384);         \
    g2l16(gA1 + (ko), lA + (d) * 32768 + (ksub) * 16384 + 8192);  \
  }
#define STAGE_B(d, ksub, ko)                                      \
  {                                                               \
    g2l16(gB0 + (ko), lB + (d) * 32768 + (ksub) * 16384);         \
    g2l16(gB1 + (ko), lB + (d) * 32768 + (ksub) * 16384 + 8192);  \
  }

  // ---- read side: swizzled lane offsets ----
  const int rd = (lr * 64 + lq * 16) ^ ((lr & 6) << 3);
  const char* rA = smem + wm * 8192 + rd;           // + d*32768 + ks*16384 + fi*1024
  const char* rB = smem + 65536 + wn * 4096 + rd;   // + d*32768 + ks*16384 + fj*1024

#define LDA(d, ks, fi) (*(const bf16x8*)(rA + (d) * 32768 + (ks) * 16384 + (fi) * 1024))
#define LDB(d, ks, fj) (*(const bf16x8*)(rB + (d) * 32768 + (ks) * 16384 + (fj) * 1024))

  f32x4 acc[8][4];
#pragma unroll
  for (int i = 0; i < 8; i++)
#pragma unroll
    for (int j = 0; j < 4; j++) {
      f32x4 z = {0.0f, 0.0f, 0.0f, 0.0f};
      acc[i][j] = z;
    }

#define MFMA_COLS(c0_, c1_)                                                              \
  _Pragma("unroll") for (int fi = 0; fi < 8; ++fi) {                                     \
    acc[fi][c0_] = __builtin_amdgcn_mfma_f32_16x16x32_bf16(af[fi], b0, acc[fi][c0_], 0, 0, 0); \
    acc[fi][c1_] = __builtin_amdgcn_mfma_f32_16x16x32_bf16(af[fi], b1, acc[fi][c1_], 0, 0, 0); \
  }

#define TILE(d, kn1, kn2)                                         \
  {                                                               \
    bf16x8 af[8];                                                 \
    _Pragma("unroll") for (int fi = 0; fi < 8; ++fi) af[fi] = LDA(d, 0, fi); \
    bf16x8 b0 = LDB(d, 0, 0), b1 = LDB(d, 0, 1);                  \
    STAGE_B((d) ^ 1, 1, (kn1) + 32);                              \
    SBAR;                                                         \
    __builtin_amdgcn_s_setprio(1);                                \
    MFMA_COLS(0, 1);                                              \
    __builtin_amdgcn_s_setprio(0);                                \
    SBAR;                                                         \
    b0 = LDB(d, 0, 2); b1 = LDB(d, 0, 3);                         \
    STAGE_A(d, 0, kn2);                                           \
    SBAR;                                                         \
    __builtin_amdgcn_s_setprio(1);                                \
    MFMA_COLS(2, 3);                                              \
    __builtin_amdgcn_s_setprio(0);                                \
    SBAR;                                                         \
    _Pragma("unroll") for (int fi = 0; fi < 8; ++fi) af[fi] = LDA(d, 1, fi); \
    b0 = LDB(d, 1, 0); b1 = LDB(d, 1, 1);                         \
    STAGE_B(d, 0, kn2);                                           \
    SBAR;                                                         \
    __builtin_amdgcn_s_setprio(1);                                \
    MFMA_COLS(0, 1);                                              \
    __builtin_amdgcn_s_setprio(0);                                \
    SBAR;                                                         \
    b0 = LDB(d, 1, 2); b1 = LDB(d, 1, 3);                         \
    STAGE_A(d, 1, (kn2) + 32);                                    \
    SBAR;                                                         \
    __builtin_amdgcn_s_setprio(1);                                \
    MFMA_COLS(2, 3);                                              \
    __builtin_amdgcn_s_setprio(0);                                \
    FENCE;                                                        \
    asm volatile("s_waitcnt vmcnt(6)" ::: "memory");              \
    __builtin_amdgcn_s_barrier();                                 \
    FENCE;                                                        \
  }

  const int NT = K >> 6;  // K-tiles of 64; NT is even and >= 2 for both GEMMs

  // prologue: tile0 (4 halves) + first 3 halves of tile1, then wait to 6 outstanding
  STAGE_A(0, 0, 0);
  STAGE_B(0, 0, 0);
  STAGE_A(0, 1, 32);
  STAGE_B(0, 1, 32);
  STAGE_A(1, 0, 64);
  STAGE_B(1, 0, 64);
  STAGE_A(1, 1, 96);
  FENCE;
  asm volatile("s_waitcnt vmcnt(6)" ::: "memory");
  __builtin_amdgcn_s_barrier();
  FENCE;

  for (int t = 0; t < NT; t += 2) {
    const int k2 = (t + 2 < NT ? t + 2 : NT - 1) << 6;
    const int k3 = (t + 3 < NT ? t + 3 : NT - 1) << 6;
    TILE(0, (t + 1) << 6, k2);
    TILE(1, k2, k3);
  }
  asm volatile("s_waitcnt vmcnt(0)" ::: "memory");  // drain tail prefetches before LDS dealloc

  // ---------------- epilogue (same math as verified kernel) ----------------
  const float ts = __uint_as_float(*amaxp) / 2688.0f;
  if (EPI == 0) {
    float* o = (float*)Out;
#pragma unroll
    for (int fi = 0; fi < 8; ++fi)
#pragma unroll
      for (int fj = 0; fj < 4; ++fj) {
        size_t col = brow0 + (size_t)(wn << 6) + fj * 16 + lr;
#pragma unroll
        for (int r = 0; r < 4; ++r) {
          size_t row = arow0 + (size_t)(wm << 7) + fi * 16 + lq * 4 + r;
          o[row * (size_t)N + col] = acc[fi][fj][r] * ts;
        }
      }
  } else {
    ushort* o = (ushort*)Out;
    const float tsh = *tshp;
#pragma unroll
    for (int fi = 0; fi < 8; ++fi)
#pragma unroll
      for (int fj = 0; fj < 4; ++fj) {
#pragma unroll
        for (int r = 0; r < 4; ++r) {
          float h = acc[fi][fj][r] * ts;
          float g = 0.5f * h * (1.0f + erff(h * 0.707106781186547524f));
          float m = fabsf(g);
          m = fmaxf(m, __shfl_xor(m, 1, 64));
          m = fmaxf(m, __shfl_xor(m, 2, 64));
          m = fmaxf(m, __shfl_xor(m, 4, 64));
          m = fmaxf(m, __shfl_xor(m, 8, 64));
          float bs = fmaxf(round_e4m3_pos(m / (6.0f * tsh)), 0x1p-6f);
          float eff = bs * tsh;
          float val = round_e2m1(g / eff) * eff;
          size_t row = arow0 + (size_t)(wm << 7) + fi * 16 + lq * 4 + r;
          size_t col = brow0 + (size_t)(wn << 6) + fj * 16 + lr;
          o[row * (size_t)N + col] = f32_to_bf16_bits(val);
        }
      }
  }
#undef STAGE_A
#undef STAGE_B
#undef LDA
#undef LDB
#undef MFMA_COLS
#undef TILE
}

// ---------------- launch ----------------

extern "C" void kernel_launch(void* const* d_in, const int* in_sizes, int n_in,
                              void* d_out, int out_size, void* d_ws, size_t ws_size,
                              hipStream_t stream) {
  const float* x = (const float*)d_in[0];
  const float* w1 = (const float*)d_in[1];
  const float* w2 = (const float*)d_in[2];
  const float* in_scale = (const float*)d_in[3];
  const float* hid_scale = (const float*)d_in[4];

  const int Bm = 8192, IN = 4096, HID = 16384, OUTN = 4096;

  unsigned* amax = (unsigned*)d_ws;
  ushort* xq = (ushort*)((char*)d_ws + 256);
  ushort* w1q = xq + (size_t)Bm * IN;
  ushort* w2q = w1q + (size_t)HID * IN;
  ushort* hq = w2q + (size_t)OUTN * HID;
  size_t need = 256 + 2 * ((size_t)Bm * IN + (size_t)HID * IN + (size_t)OUTN * HID +
                           (size_t)Bm * HID);
  if (ws_size < need) return;

  init_kernel<<<1, 64, 0, stream>>>(amax);
  amax_kernel<<<2048, 256, 0, stream>>>((const float4*)w1, amax + 0, (HID * IN) / 4);
  amax_kernel<<<2048, 256, 0, stream>>>((const float4*)w2, amax + 1, (OUTN * HID) / 4);

  quant_kernel<<<(Bm * IN / 4) / 256, 256, 0, stream>>>((const float4*)x, xq, in_scale,
                                                        amax, 0, Bm * IN / 4);
  quant_kernel<<<(HID * IN / 4) / 256, 256, 0, stream>>>((const float4*)w1, w1q, in_scale,
                                                         amax + 0, 1, HID * IN / 4);
  quant_kernel<<<(OUTN * HID / 4) / 256, 256, 0, stream>>>((const float4*)w2, w2q, in_scale,
                                                           amax + 1, 1, OUTN * HID / 4);

  gemm256<1><<<(Bm / 256) * (HID / 256), 512, 0, stream>>>(xq, w1q, (void*)hq, amax + 0,
                                                           hid_scale, HID, IN);
  gemm256<0><<<(Bm / 256) * (OUTN / 256), 512, 0, stream>>>(hq, w2q, d_out, amax + 1,
                                                            hid_scale, OUTN, HID);
}

// Round 2
// 3757.994 us; speedup vs baseline: 1.0044x; 1.0044x over previous
//
#include <hip/hip_runtime.h>

typedef __bf16 bf16x8 __attribute__((ext_vector_type(8)));
typedef float f32x4 __attribute__((ext_vector_type(4)));

// ---------------- numerics helpers (bit-exact vs reference) ----------------

__device__ __forceinline__ unsigned short f32_to_bf16_bits(float v) {
  return (unsigned short)(__float_as_uint(v) >> 16);
}

__device__ __forceinline__ float round_e4m3_pos(float a) {
  float am = fmaxf(a, 0x1p-9f);
  int e = (int)((__float_as_uint(am) >> 23) & 255) - 127;
  e = e < -6 ? -6 : (e > 8 ? 8 : e);
  float s = __int_as_float((e + 127) << 23);
  float q = rintf(a / s * 8.0f) * 0.125f * s;
  return fminf(q, 448.0f);
}

__device__ __forceinline__ float round_e2m1(float x) {
  float a = fabsf(x);
  float am = fmaxf(a, 0x1p-3f);
  int e = (int)((__float_as_uint(am) >> 23) & 255) - 127;
  e = e < 0 ? 0 : (e > 2 ? 2 : e);
  float s = __int_as_float((e + 127) << 23);
  float q = rintf(a / s * 2.0f) * 0.5f * s;
  q = fminf(q, 6.0f);
  return x < 0.0f ? -q : q;
}

__device__ __forceinline__ void g2l16(const void* g, void* l) {
  __builtin_amdgcn_global_load_lds(
      (__attribute__((address_space(1))) void*)g,
      (__attribute__((address_space(3))) void*)l, 16, 0, 0);
}

// inline-asm LDS read: opaque to SIInsertWaitcnts' LDS-DMA alias tracking, so
// the compiler cannot insert per-phase vmcnt drains; ordering vs global_load_lds
// is enforced by the programmer's counted vmcnt + barriers (HK/m201 mechanism).
__device__ __forceinline__ bf16x8 ldsr(unsigned addr) {
  bf16x8 r;
  asm volatile("ds_read_b128 %0, %1" : "=v"(r) : "v"(addr));
  return r;
}

// ---------------- prep kernels (unchanged, harness-verified) ----------------

__global__ void init_kernel(unsigned* p) {
  if (threadIdx.x < 2) p[threadIdx.x] = 0u;
}

__global__ __launch_bounds__(256) void amax_kernel(const float4* __restrict__ w,
                                                   unsigned* __restrict__ out, int n4) {
  float m = 0.0f;
  int stride = gridDim.x * 256;
  for (int i = blockIdx.x * 256 + threadIdx.x; i < n4; i += stride) {
    float4 v = w[i];
    m = fmaxf(m, fmaxf(fmaxf(fabsf(v.x), fabsf(v.y)), fmaxf(fabsf(v.z), fabsf(v.w))));
  }
#pragma unroll
  for (int o = 32; o > 0; o >>= 1) m = fmaxf(m, __shfl_xor(m, o, 64));
  if ((threadIdx.x & 63) == 0) atomicMax(out, __float_as_uint(m));
}

__global__ __launch_bounds__(256) void quant_kernel(const float4* __restrict__ in,
                                                    ushort* __restrict__ outq,
                                                    const float* __restrict__ tsp,
                                                    const unsigned* __restrict__ amaxp,
                                                    int isw, int n4) {
  int i = blockIdx.x * 256 + threadIdx.x;
  if (i >= n4) return;
  float ts = isw ? (__uint_as_float(*amaxp) / 2688.0f) : *tsp;
  float4 v = in[i];
  float m = fmaxf(fmaxf(fabsf(v.x), fabsf(v.y)), fmaxf(fabsf(v.z), fabsf(v.w)));
  m = fmaxf(m, __shfl_xor(m, 1, 64));
  m = fmaxf(m, __shfl_xor(m, 2, 64));
  float bs = fmaxf(round_e4m3_pos(m / (6.0f * ts)), 0x1p-6f);
  float eff = bs * ts;
  float osc = isw ? bs : eff;
  ushort4 o;
  o.x = f32_to_bf16_bits(round_e2m1(v.x / eff) * osc);
  o.y = f32_to_bf16_bits(round_e2m1(v.y / eff) * osc);
  o.z = f32_to_bf16_bits(round_e2m1(v.z / eff) * osc);
  o.w = f32_to_bf16_bits(round_e2m1(v.w / eff) * osc);
  *(ushort4*)(outq + (size_t)i * 4) = o;
}

// ---------------- GEMM: 256x256 tile, BK=64, 8 waves, 8-phase pipeline ----------------
// Identical geometry / LDS map / swizzle / barrier+stage ledger as the refcheck-passed
// round-1 kernel. Changes: asm ds_read + explicit lgkmcnt(0)+sched_barrier(0) before
// MFMA clusters (rule #18), bare barriers, no memory clobbers -> counted vmcnt(6) is
// the ONLY vm wait in the main loop.

template <int EPI>
__global__ __launch_bounds__(512, 2) void gemm256(const ushort* __restrict__ A,
                                                  const ushort* __restrict__ B,
                                                  void* __restrict__ Out,
                                                  const unsigned* __restrict__ amaxp,
                                                  const float* __restrict__ tshp,
                                                  int N, int K) {
  __shared__ __align__(16) char smem[131072];
  const int tid = threadIdx.x;
  const int lane = tid & 63, wv = tid >> 6;
  const int wm = wv >> 2, wn = wv & 3;   // 2 x 4 wave grid
  const int lr = lane & 15, lq = lane >> 4;

  // XCD-aware bijective swizzle (grid %8 == 0 for both GEMMs here)
  const int nwg = gridDim.x;
  const int wg = (blockIdx.x & 7) * (nwg >> 3) + (blockIdx.x >> 3);
  const int ntiles = N >> 8;
  const int bm = wg / ntiles, bn = wg - bm * ntiles;
  const size_t arow0 = (size_t)bm << 8, brow0 = (size_t)bn << 8;

  // ---- staging: per-thread source coords (inverse-swizzled), linear LDS dest ----
  const int sw = (tid << 4) ^ ((tid << 1) & 0x30);  // swizzled unit-offset of chunk tid
  const int srow = sw >> 6;                          // 0..127
  const int skc = (sw & 63) >> 1;                    // element offset in k-half
  const ushort* gA0 = A + (arow0 + srow) * (size_t)K + skc;
  const ushort* gA1 = gA0 + (size_t)128 * K;
  const ushort* gB0 = B + (brow0 + srow) * (size_t)K + skc;
  const ushort* gB1 = gB0 + (size_t)128 * K;
  char* lA = smem + tid * 16;
  char* lB = smem + 65536 + tid * 16;

#define STAGE_A(d, ksub, ko)                                      \
  {                                                               \
    g2l16(gA0 + (ko), lA + (d) * 32768 + (ksub) * 16384);         \
    g2l16(gA1 + (ko), lA + (d) * 32768 + (ksub) * 16384 + 8192);  \
  }
#define STAGE_B(d, ksub, ko)                                      \
  {                                                               \
    g2l16(gB0 + (ko), lB + (d) * 32768 + (ksub) * 16384);         \
    g2l16(gB1 + (ko), lB + (d) * 32768 + (ksub) * 16384 + 8192);  \
  }

  // ---- read side: swizzled lane offsets as 32-bit LDS byte addresses ----
  const int rd = (lr * 64 + lq * 16) ^ ((lr & 6) << 3);
  const unsigned lbase =
      (unsigned)(size_t)(__attribute__((address_space(3))) char*)smem;
  const unsigned va = lbase + wm * 8192 + rd;            // + d*32768 + ks*16384 + fi*1024
  const unsigned vb = lbase + 65536 + wn * 4096 + rd;    // + d*32768 + ks*16384 + fj*1024

  f32x4 acc[8][4];
#pragma unroll
  for (int i = 0; i < 8; i++)
#pragma unroll
    for (int j = 0; j < 4; j++) {
      f32x4 z = {0.0f, 0.0f, 0.0f, 0.0f};
      acc[i][j] = z;
    }

#define MFMA_COLS(c0_, c1_)                                                              \
  _Pragma("unroll") for (int fi = 0; fi < 8; ++fi) {                                     \
    acc[fi][c0_] = __builtin_amdgcn_mfma_f32_16x16x32_bf16(af[fi], b0, acc[fi][c0_], 0, 0, 0); \
    acc[fi][c1_] = __builtin_amdgcn_mfma_f32_16x16x32_bf16(af[fi], b1, acc[fi][c1_], 0, 0, 0); \
  }

  // barrier -> wait LDS reads -> pin -> MFMA cluster -> pin (rule #18)
#define PH_MFMA(c0_, c1_)                        \
  __builtin_amdgcn_s_barrier();                  \
  asm volatile("s_waitcnt lgkmcnt(0)");          \
  __builtin_amdgcn_sched_barrier(0);             \
  __builtin_amdgcn_s_setprio(1);                 \
  MFMA_COLS(c0_, c1_);                           \
  __builtin_amdgcn_s_setprio(0);                 \
  __builtin_amdgcn_sched_barrier(0);

#define TILE(d, kn1, kn2)                                                 \
  {                                                                       \
    bf16x8 af[8], b0, b1;                                                 \
    _Pragma("unroll") for (int fi = 0; fi < 8; ++fi)                      \
        af[fi] = ldsr(va + (d) * 32768 + fi * 1024);                      \
    b0 = ldsr(vb + (d) * 32768 + 0 * 1024);                               \
    b1 = ldsr(vb + (d) * 32768 + 1 * 1024);                               \
    STAGE_B((d) ^ 1, 1, (kn1) + 32);                                      \
    PH_MFMA(0, 1);                                                        \
    __builtin_amdgcn_s_barrier();                                         \
    b0 = ldsr(vb + (d) * 32768 + 2 * 1024);                               \
    b1 = ldsr(vb + (d) * 32768 + 3 * 1024);                               \
    STAGE_A(d, 0, kn2);                                                   \
    PH_MFMA(2, 3);                                                        \
    __builtin_amdgcn_s_barrier();                                         \
    _Pragma("unroll") for (int fi = 0; fi < 8; ++fi)                      \
        af[fi] = ldsr(va + (d) * 32768 + 16384 + fi * 1024);              \
    b0 = ldsr(vb + (d) * 32768 + 16384 + 0 * 1024);                       \
    b1 = ldsr(vb + (d) * 32768 + 16384 + 1 * 1024);                       \
    STAGE_B(d, 0, kn2);                                                   \
    PH_MFMA(0, 1);                                                        \
    __builtin_amdgcn_s_barrier();                                         \
    b0 = ldsr(vb + (d) * 32768 + 16384 + 2 * 1024);                       \
    b1 = ldsr(vb + (d) * 32768 + 16384 + 3 * 1024);                       \
    STAGE_A(d, 1, (kn2) + 32);                                            \
    PH_MFMA(2, 3);                                                        \
    asm volatile("s_waitcnt vmcnt(6)");                                   \
    __builtin_amdgcn_s_barrier();                                         \
  }

  const int NT = K >> 6;  // K-tiles of 64; even for both GEMMs

  // prologue: tile0 (4 halves) + first 3 halves of tile1, wait to 6 outstanding
  STAGE_A(0, 0, 0);
  STAGE_B(0, 0, 0);
  STAGE_A(0, 1, 32);
  STAGE_B(0, 1, 32);
  STAGE_A(1, 0, 64);
  STAGE_B(1, 0, 64);
  STAGE_A(1, 1, 96);
  asm volatile("s_waitcnt vmcnt(6)");
  __builtin_amdgcn_s_barrier();

  for (int t = 0; t < NT; t += 2) {
    const int k2 = (t + 2 < NT ? t + 2 : NT - 1) << 6;
    const int k3 = (t + 3 < NT ? t + 3 : NT - 1) << 6;
    TILE(0, (t + 1) << 6, k2);
    TILE(1, k2, k3);
  }
  asm volatile("s_waitcnt vmcnt(0)");  // drain tail prefetches

  // ---------------- epilogue (same math as verified kernel) ----------------
  const float ts = __uint_as_float(*amaxp) / 2688.0f;
  if (EPI == 0) {
    float* o = (float*)Out;
#pragma unroll
    for (int fi = 0; fi < 8; ++fi)
#pragma unroll
      for (int fj = 0; fj < 4; ++fj) {
        size_t col = brow0 + (size_t)(wn << 6) + fj * 16 + lr;
#pragma unroll
        for (int r = 0; r < 4; ++r) {
          size_t row = arow0 + (size_t)(wm << 7) + fi * 16 + lq * 4 + r;
          o[row * (size_t)N + col] = acc[fi][fj][r] * ts;
        }
      }
  } else {
    ushort* o = (ushort*)Out;
    const float tsh = *tshp;
#pragma unroll
    for (int fi = 0; fi < 8; ++fi)
#pragma unroll
      for (int fj = 0; fj < 4; ++fj) {
#pragma unroll
        for (int r = 0; r < 4; ++r) {
          float h = acc[fi][fj][r] * ts;
          float g = 0.5f * h * (1.0f + erff(h * 0.707106781186547524f));
          float m = fabsf(g);
          m = fmaxf(m, __shfl_xor(m, 1, 64));
          m = fmaxf(m, __shfl_xor(m, 2, 64));
          m = fmaxf(m, __shfl_xor(m, 4, 64));
          m = fmaxf(m, __shfl_xor(m, 8, 64));
          float bs = fmaxf(round_e4m3_pos(m / (6.0f * tsh)), 0x1p-6f);
          float eff = bs * tsh;
          float val = round_e2m1(g / eff) * eff;
          size_t row = arow0 + (size_t)(wm << 7) + fi * 16 + lq * 4 + r;
          size_t col = brow0 + (size_t)(wn << 6) + fj * 16 + lr;
          o[row * (size_t)N + col] = f32_to_bf16_bits(val);
        }
      }
  }
#undef STAGE_A
#undef STAGE_B
#undef MFMA_COLS
#undef PH_MFMA
#undef TILE
}

// ---------------- launch ----------------

extern "C" void kernel_launch(void* const* d_in, const int* in_sizes, int n_in,
                              void* d_out, int out_size, void* d_ws, size_t ws_size,
                              hipStream_t stream) {
  const float* x = (const float*)d_in[0];
  const float* w1 = (const float*)d_in[1];
  const float* w2 = (const float*)d_in[2];
  const float* in_scale = (const float*)d_in[3];
  const float* hid_scale = (const float*)d_in[4];

  const int Bm = 8192, IN = 4096, HID = 16384, OUTN = 4096;

  unsigned* amax = (unsigned*)d_ws;
  ushort* xq = (ushort*)((char*)d_ws + 256);
  ushort* w1q = xq + (size_t)Bm * IN;
  ushort* w2q = w1q + (size_t)HID * IN;
  ushort* hq = w2q + (size_t)OUTN * HID;
  size_t need = 256 + 2 * ((size_t)Bm * IN + (size_t)HID * IN + (size_t)OUTN * HID +
                           (size_t)Bm * HID);
  if (ws_size < need) return;

  init_kernel<<<1, 64, 0, stream>>>(amax);
  amax_kernel<<<2048, 256, 0, stream>>>((const float4*)w1, amax + 0, (HID * IN) / 4);
  amax_kernel<<<2048, 256, 0, stream>>>((const float4*)w2, amax + 1, (OUTN * HID) / 4);

  quant_kernel<<<(Bm * IN / 4) / 256, 256, 0, stream>>>((const float4*)x, xq, in_scale,
                                                        amax, 0, Bm * IN / 4);
  quant_kernel<<<(HID * IN / 4) / 256, 256, 0, stream>>>((const float4*)w1, w1q, in_scale,
                                                         amax + 0, 1, HID * IN / 4);
  quant_kernel<<<(OUTN * HID / 4) / 256, 256, 0, stream>>>((const float4*)w2, w2q, in_scale,
                                                           amax + 1, 1, OUTN * HID / 4);

  gemm256<1><<<(Bm / 256) * (HID / 256), 512, 0, stream>>>(xq, w1q, (void*)hq, amax + 0,
                                                           hid_scale, HID, IN);
  gemm256<0><<<(Bm / 256) * (OUTN / 256), 512, 0, stream>>>(hq, w2q, d_out, amax + 1,
                                                            hid_scale, OUTN, HID);
}